// Round 3
// baseline (505.599 us; speedup 1.0000x reference)
//
#include <hip/hip_runtime.h>

// B=2, S=2048, E=1024, H=16, HD=KD=VD=64. fp32 I/O, bf16 MFMA internals.
#define BB 2
#define SS 2048
#define EE 1024
#define HH 16
#define HD 64
#define SCALE 0.125f

typedef __attribute__((ext_vector_type(8))) short short8;
typedef __attribute__((ext_vector_type(4))) float float4v;
typedef __attribute__((ext_vector_type(4))) unsigned short ushort4v;

__device__ __forceinline__ float bf2f(unsigned short u) {
  unsigned int v = ((unsigned int)u) << 16;
  return __uint_as_float(v);
}
__device__ __forceinline__ unsigned short f2bf(float f) {
  unsigned int u = __float_as_uint(f);
  unsigned int lsb = (u >> 16) & 1u;
  u += 0x7fffu + lsb;           // RNE
  return (unsigned short)(u >> 16);
}

// ---------------------------------------------------------------------------
// Kernel A: QKV projection (fp32 in, bf16 out).
// ---------------------------------------------------------------------------
__global__ __launch_bounds__(256) void qkv_kernel(
    const float* __restrict__ x,
    const float* __restrict__ Wq, const float* __restrict__ bq,
    const float* __restrict__ Wk, const float* __restrict__ bk,
    const float* __restrict__ Wv, const float* __restrict__ bv,
    unsigned short* __restrict__ Q, unsigned short* __restrict__ K,
    unsigned short* __restrict__ Vt)
{
  __shared__ float sW[3 * 4096];
  __shared__ float sB[3 * 64];
  int tid = threadIdx.x;
  for (int i = tid; i < 4096; i += 256) {
    sW[i]        = Wq[i];
    sW[4096 + i] = Wk[i];
    sW[8192 + i] = Wv[i];
  }
  if (tid < 64)        sB[tid] = bq[tid];
  else if (tid < 128)  sB[tid] = bk[tid - 64];
  else if (tid < 192)  sB[tid] = bv[tid - 128];
  __syncthreads();

  int wv = tid >> 6, lane = tid & 63;
  int rowBase = blockIdx.x * 64 + wv * 16;
  for (int rr = 0; rr < 16; ++rr) {
    int row = rowBase + rr;          // bh*S + s
    int bh = row >> 11;
    int s  = row & 2047;
    int b = bh >> 4, h = bh & 15;
    const float* xp = x + ((size_t)(b * SS + s)) * EE + h * 64;
    float xr = xp[lane];
    float aq = sB[lane], ak = sB[64 + lane], av = sB[128 + lane];
#pragma unroll
    for (int d = 0; d < 64; ++d) {
      float xd = __shfl(xr, d, 64);
      aq += xd * sW[d * 64 + lane];
      ak += xd * sW[4096 + d * 64 + lane];
      av += xd * sW[8192 + d * 64 + lane];
    }
    size_t qoff = (size_t)row * 64 + lane;
    Q[qoff] = f2bf(aq);
    K[qoff] = f2bf(ak);
    Vt[((size_t)bh * 64 + lane) * SS + s] = f2bf(av);
  }
}

// ---------------------------------------------------------------------------
// Kernel B: transpose Wo (1024x1024 fp32, [k][n]) -> WoT ([n][k]) bf16.
// ---------------------------------------------------------------------------
__global__ __launch_bounds__(256) void transpose_wo(
    const float* __restrict__ Wo, unsigned short* __restrict__ WoT)
{
  __shared__ unsigned short t[64 * 65];
  int tid = threadIdx.x;
  int k0 = (blockIdx.x >> 4) * 64;
  int n0 = (blockIdx.x & 15) * 64;
#pragma unroll
  for (int i = 0; i < 16; ++i) {
    int idx = tid + i * 256;
    int k = idx >> 6, n = idx & 63;
    t[n * 65 + k] = f2bf(Wo[(size_t)(k0 + k) * 1024 + n0 + n]);
  }
  __syncthreads();
#pragma unroll
  for (int i = 0; i < 16; ++i) {
    int idx = tid + i * 256;
    int n = idx >> 6, k = idx & 63;
    WoT[(size_t)(n0 + n) * 1024 + k0 + k] = t[n * 65 + k];
  }
}

// ---------------------------------------------------------------------------
// Kernel C: maskS = bf16(mask * SCALE * log2(e)) so attn uses exp2 directly.
// 4M elems, float4 reads, ushort4 writes. 4096 blocks x 256 threads x 4.
// ---------------------------------------------------------------------------
__global__ __launch_bounds__(256) void mask_prep(
    const float* __restrict__ mask, unsigned short* __restrict__ maskS)
{
  const float c = SCALE * 1.44269504088896f;
  int i = blockIdx.x * 256 + threadIdx.x;
  float4 v = ((const float4*)mask)[i];
  ushort4v r;
  r.x = f2bf(v.x * c);
  r.y = f2bf(v.y * c);
  r.z = f2bf(v.z * c);
  r.w = f2bf(v.w * c);
  *(ushort4v*)(maskS + (size_t)i * 4) = r;
}

// ---------------------------------------------------------------------------
// Kernel D: flash attention, barrier-free + software-pipelined.
// 1 wave = 16 q-rows. P transform via wave-PRIVATE double-buffered LDS with
// s_waitcnt lgkmcnt(0) only (no __syncthreads — waves fully decoupled).
// Next s-step's K/V/mask frags prefetched into registers (vmcnt overlap).
// P row stride 72 ushorts (144B): write conflicts 8-way -> 4-way, b128 reads
// stay 16B-aligned.
// ---------------------------------------------------------------------------
__global__ __launch_bounds__(256, 3) void attn_kernel(
    const unsigned short* __restrict__ Q, const unsigned short* __restrict__ K,
    const unsigned short* __restrict__ Vt, const unsigned short* __restrict__ maskS,
    unsigned short* __restrict__ AO)
{
  __shared__ unsigned short lds_p[4 * 2 * 16 * 72];
  int tid = threadIdx.x, wv = tid >> 6, lane = tid & 63;
  int li = lane & 15, g = lane >> 4;

  int tile = blockIdx.x * 4 + wv;
  int bh = tile >> 7;
  int q0 = (tile & 127) << 4;

  const unsigned short* Qbase = Q + ((size_t)bh * SS + q0 + li) * 64;
  short8 qf0 = *(const short8*)(Qbase + g * 8);
  short8 qf1 = *(const short8*)(Qbase + 32 + g * 8);

  const unsigned short* Kb = K + ((size_t)bh * SS + li) * 64 + g * 8;
  const unsigned short* Vb = Vt + ((size_t)bh * 64 + li) * SS + g * 8;
  const unsigned short* Mb = maskS + (size_t)(q0 + g * 4) * SS + li;

  float4v acc_o[4] = {{0,0,0,0},{0,0,0,0},{0,0,0,0},{0,0,0,0}};
  float den[4] = {0.f, 0.f, 0.f, 0.f};
  unsigned short* p0 = lds_p + wv * (2 * 16 * 72);
  unsigned short* p1 = p0 + 16 * 72;

  short8 kA0[2], kA1[2], vA[4]; unsigned short mA[8];
  short8 kB0[2], kB1[2], vB[4]; unsigned short mB[8];

  auto loadS = [&](int s0, short8* k0, short8* k1, short8* v, unsigned short* m) {
#pragma unroll
    for (int sb = 0; sb < 2; ++sb) {
      const unsigned short* kp = Kb + (size_t)(s0 + sb * 16) * 64;
      k0[sb] = *(const short8*)(kp);
      k1[sb] = *(const short8*)(kp + 32);
    }
#pragma unroll
    for (int nb = 0; nb < 4; ++nb)
      v[nb] = *(const short8*)(Vb + (size_t)nb * 16 * SS + s0);
#pragma unroll
    for (int sb = 0; sb < 2; ++sb)
#pragma unroll
      for (int r = 0; r < 4; ++r)
        m[sb * 4 + r] = Mb[(size_t)r * SS + s0 + sb * 16];
  };

  auto step = [&](short8* k0, short8* k1, short8* v, unsigned short* m,
                  unsigned short* pbuf) {
    float4v pa[2];
#pragma unroll
    for (int sb = 0; sb < 2; ++sb) {
      float4v a = {0, 0, 0, 0};
      a = __builtin_amdgcn_mfma_f32_16x16x32_bf16(qf0, k0[sb], a, 0, 0, 0);
      a = __builtin_amdgcn_mfma_f32_16x16x32_bf16(qf1, k1[sb], a, 0, 0, 0);
      pa[sb] = a;
    }
#pragma unroll
    for (int sb = 0; sb < 2; ++sb)
#pragma unroll
      for (int r = 0; r < 4; ++r) {
        float p = __builtin_amdgcn_exp2f(pa[sb][r] * bf2f(m[sb * 4 + r]));
        den[r] += p;
        pbuf[(g * 4 + r) * 72 + sb * 16 + li] = f2bf(p);
      }
    asm volatile("s_waitcnt lgkmcnt(0)" ::: "memory");
    short8 pf = *(const short8*)(pbuf + li * 72 + g * 8);
#pragma unroll
    for (int nb = 0; nb < 4; ++nb)
      acc_o[nb] = __builtin_amdgcn_mfma_f32_16x16x32_bf16(pf, v[nb], acc_o[nb], 0, 0, 0);
  };

  loadS(0, kA0, kA1, vA, mA);
  for (int s0 = 0; s0 < SS; s0 += 64) {
    loadS(s0 + 32, kB0, kB1, vB, mB);
    step(kA0, kA1, vA, mA, p0);
    int sA = (s0 + 64 < SS) ? (s0 + 64) : 0;   // clamped redundant tail load
    loadS(sA, kA0, kA1, vA, mA);
    step(kB0, kB1, vB, mB, p1);
  }

#pragma unroll
  for (int r = 0; r < 4; ++r) {
    den[r] += __shfl_xor(den[r], 1, 64);
    den[r] += __shfl_xor(den[r], 2, 64);
    den[r] += __shfl_xor(den[r], 4, 64);
    den[r] += __shfl_xor(den[r], 8, 64);
  }

  int b = bh >> 4, h = bh & 15;
#pragma unroll
  for (int nb = 0; nb < 4; ++nb)
#pragma unroll
    for (int r = 0; r < 4; ++r) {
      float o = acc_o[nb][r] / den[r];
      int s = q0 + g * 4 + r;
      AO[((size_t)(b * SS + s)) * EE + h * 64 + nb * 16 + li] = f2bf(o);
    }
}

// ---------------------------------------------------------------------------
// Kernel E: out = AO(4096x1024 bf16) @ Wo + bo (fp32 out), prefetched.
// ---------------------------------------------------------------------------
__global__ __launch_bounds__(256) void out_gemm(
    const unsigned short* __restrict__ AO, const unsigned short* __restrict__ WoT,
    const float* __restrict__ bo, float* __restrict__ out)
{
  int tid = threadIdx.x, wv = tid >> 6, lane = tid & 63;
  int li = lane & 15, g = lane >> 4;
  int m0 = (blockIdx.x >> 4) * 64 + wv * 16;
  int n0 = (blockIdx.x & 15) * 64;

  const unsigned short* Ab = AO + (size_t)(m0 + li) * 1024 + g * 8;
  const unsigned short* Bb = WoT + (size_t)(n0 + li) * 1024 + g * 8;

  float4v acc[4] = {{0,0,0,0},{0,0,0,0},{0,0,0,0},{0,0,0,0}};
  short8 aA, bA[4], aB, bB[4];

  auto loadF = [&](int k0, short8& a, short8* bfr) {
    a = *(const short8*)(Ab + k0);
#pragma unroll
    for (int nb = 0; nb < 4; ++nb)
      bfr[nb] = *(const short8*)(Bb + (size_t)nb * 16 * 1024 + k0);
  };

  loadF(0, aA, bA);
  for (int k0 = 0; k0 < 1024; k0 += 64) {
    loadF(k0 + 32, aB, bB);
#pragma unroll
    for (int nb = 0; nb < 4; ++nb)
      acc[nb] = __builtin_amdgcn_mfma_f32_16x16x32_bf16(aA, bA[nb], acc[nb], 0, 0, 0);
    int kA = (k0 + 64 < 1024) ? (k0 + 64) : 0;
    loadF(kA, aA, bA);
#pragma unroll
    for (int nb = 0; nb < 4; ++nb)
      acc[nb] = __builtin_amdgcn_mfma_f32_16x16x32_bf16(aB, bB[nb], acc[nb], 0, 0, 0);
  }
#pragma unroll
  for (int nb = 0; nb < 4; ++nb) {
    float bof = bo[n0 + nb * 16 + li];
#pragma unroll
    for (int r = 0; r < 4; ++r)
      out[(size_t)(m0 + g * 4 + r) * 1024 + n0 + nb * 16 + li] = acc[nb][r] + bof;
  }
}

// ---------------------------------------------------------------------------
extern "C" void kernel_launch(void* const* d_in, const int* in_sizes, int n_in,
                              void* d_out, int out_size, void* d_ws, size_t ws_size,
                              hipStream_t stream) {
  const float* x    = (const float*)d_in[0];
  const float* mask = (const float*)d_in[1];
  const float* Wq   = (const float*)d_in[2];
  const float* bq   = (const float*)d_in[3];
  const float* Wk   = (const float*)d_in[4];
  const float* bk   = (const float*)d_in[5];
  const float* Wv   = (const float*)d_in[6];
  const float* bv   = (const float*)d_in[7];
  const float* Wo   = (const float*)d_in[8];
  const float* bo   = (const float*)d_in[9];
  float* out = (float*)d_out;

  unsigned short* ws = (unsigned short*)d_ws;
  // ushort-element offsets: Q 0..4M, K 4M, Vt 8M, AO 12M, WoT 16M, maskS 17M..21M
  unsigned short* Q     = ws;
  unsigned short* K     = ws + 4194304;
  unsigned short* Vt    = ws + 8388608;
  unsigned short* AO    = ws + 12582912;
  unsigned short* WoT   = ws + 16777216;
  unsigned short* maskS = ws + 17825792;

  qkv_kernel<<<1024, 256, 0, stream>>>(x, Wq, bq, Wk, bk, Wv, bv, Q, K, Vt);
  mask_prep<<<4096, 256, 0, stream>>>(mask, maskS);
  transpose_wo<<<256, 256, 0, stream>>>(Wo, WoT);
  attn_kernel<<<1024, 256, 0, stream>>>(Q, K, Vt, maskS, AO);
  out_gemm<<<1024, 256, 0, stream>>>(AO, WoT, bo, out);
}

// Round 4
// 231.877 us; speedup vs baseline: 2.1805x; 2.1805x over previous
//
#include <hip/hip_runtime.h>

// B=2, S=2048, E=1024, H=16, HD=KD=VD=64. fp32 I/O, bf16 MFMA internals.
// R4: transaction-bound fix — all hot global accesses made contiguous per
// instruction via LDS-cooperative staging + packed V / packed mask layouts.
#define SS 2048
#define EE 1024
#define SCALE 0.125f
#define LOG2E 1.44269504088896f

typedef __attribute__((ext_vector_type(8))) short short8;
typedef __attribute__((ext_vector_type(4))) float float4v;
typedef __attribute__((ext_vector_type(8))) unsigned short ushort8;
typedef __attribute__((ext_vector_type(4))) unsigned short ushort4v;

__device__ __forceinline__ float bf2f(unsigned short u) {
  unsigned int v = ((unsigned int)u) << 16;
  return __uint_as_float(v);
}
__device__ __forceinline__ unsigned short f2bf(float f) {
  unsigned int u = __float_as_uint(f);
  unsigned int lsb = (u >> 16) & 1u;
  u += 0x7fffu + lsb;           // RNE
  return (unsigned short)(u >> 16);
}

// ---------------------------------------------------------------------------
// Kernel A: QKV projection as MFMA GEMM. Block = 64 rows (one bh), 4 waves.
// x tile staged via LDS (coalesced 256B segments), W^T staged once per block.
// Q,K row-major bf16; V packed per 32-col tile: Vp[bh][s/32][d][32].
// ---------------------------------------------------------------------------
__global__ __launch_bounds__(256) void qkv_kernel(
    const float* __restrict__ x,
    const float* __restrict__ Wq, const float* __restrict__ bq,
    const float* __restrict__ Wk, const float* __restrict__ bk,
    const float* __restrict__ Wv, const float* __restrict__ bv,
    unsigned short* __restrict__ Q, unsigned short* __restrict__ K,
    unsigned short* __restrict__ Vp)
{
  __shared__ __align__(16) unsigned short w3t[192 * 72];  // [n'=m*64+n][d]
  __shared__ __align__(16) unsigned short xt[64 * 72];    // [s_local][d]
  __shared__ float sBias[192];

  int tid = threadIdx.x;
  int bh = blockIdx.x >> 5;
  int s0blk = (blockIdx.x & 31) * 64;
  int b = bh >> 4, h = bh & 15;

  const float* Ws[3] = {Wq, Wk, Wv};
#pragma unroll 4
  for (int it = 0; it < 48; ++it) {
    int e = tid + it * 256;          // 0..12287
    int m = e >> 12, rem = e & 4095;
    int d = rem >> 6, n = rem & 63;
    w3t[(m * 64 + n) * 72 + d] = f2bf(Ws[m][rem]);
  }
  if (tid < 192) sBias[tid] = (tid < 64) ? bq[tid] : (tid < 128 ? bk[tid - 64] : bv[tid - 128]);

  const float* xbase = x + ((size_t)(b * SS + s0blk)) * EE + h * 64;
#pragma unroll
  for (int it = 0; it < 4; ++it) {
    int flat = tid + it * 256;       // 1024 float4-slots
    int row = flat >> 4, ch = flat & 15;
    float4 v = *(const float4*)(xbase + (size_t)row * EE + ch * 4);
    ushort4v u; u.x = f2bf(v.x); u.y = f2bf(v.y); u.z = f2bf(v.z); u.w = f2bf(v.w);
    *(ushort4v*)(xt + row * 72 + ch * 4) = u;
  }
  __syncthreads();

  int wv = tid >> 6, lane = tid & 63;
  int li = lane & 15, g = lane >> 4;
  int mrow = wv * 16;

  short8 af[2];
#pragma unroll
  for (int ks = 0; ks < 2; ++ks)
    af[ks] = *(const short8*)(xt + (mrow + li) * 72 + ks * 32 + g * 8);

  float4v acc[12];
#pragma unroll
  for (int i = 0; i < 12; ++i) acc[i] = (float4v){0, 0, 0, 0};
#pragma unroll
  for (int ks = 0; ks < 2; ++ks)
#pragma unroll
    for (int nb = 0; nb < 12; ++nb) {
      short8 bfr = *(const short8*)(w3t + (nb * 16 + li) * 72 + ks * 32 + g * 8);
      acc[nb] = __builtin_amdgcn_mfma_f32_16x16x32_bf16(af[ks], bfr, acc[nb], 0, 0, 0);
    }

  int srow0 = s0blk + mrow + g * 4;
#pragma unroll
  for (int nb = 0; nb < 12; ++nb) {
    float bias = sBias[nb * 16 + li];
    int mtx = nb >> 2, sub = nb & 3;
#pragma unroll
    for (int r = 0; r < 4; ++r) {
      unsigned short ob = f2bf(acc[nb][r] + bias);
      int s = srow0 + r;
      if (mtx == 0)      Q[((size_t)bh * SS + s) * 64 + sub * 16 + li] = ob;
      else if (mtx == 1) K[((size_t)bh * SS + s) * 64 + sub * 16 + li] = ob;
      else Vp[(size_t)bh * 131072 + (size_t)(s >> 5) * 2048 + (sub * 16 + li) * 32 + (s & 31)] = ob;
    }
  }
}

// ---------------------------------------------------------------------------
// Kernel C: pack mask into per-lane fragment order, folding SCALE*log2(e).
// maskP[(qt*64+t)*512 + lane*8 + sb*4 + r] =
//   bf16( mask[qt*16+g*4+r][t*32+sb*16+li] * SCALE * LOG2E ),  lane = g*16+li.
// attn then loads one contiguous b128 per lane per step.
// ---------------------------------------------------------------------------
__global__ __launch_bounds__(256) void mask_prep(
    const float* __restrict__ mask, unsigned short* __restrict__ maskP)
{
  int idx = blockIdx.x * 256 + threadIdx.x;   // 0..524287 = qt*64t*64lane
  int lane = idx & 63, t = (idx >> 6) & 63, qt = idx >> 12;
  int li = lane & 15, g = lane >> 4;
  const float c = SCALE * LOG2E;
  ushort8 o;
#pragma unroll
  for (int sb = 0; sb < 2; ++sb)
#pragma unroll
    for (int r = 0; r < 4; ++r)
      o[sb * 4 + r] = f2bf(mask[(size_t)(qt * 16 + g * 4 + r) * SS + t * 32 + sb * 16 + li] * c);
  *(ushort8*)(maskP + (size_t)idx * 8) = o;
}

// ---------------------------------------------------------------------------
// Kernel D: flash attention, block-cooperative. Block = 64 q-rows of one bh.
// Per 32-col step: K-tile(4KB)+V-tile(4KB) staged to LDS, 1 b128/thread,
// fully contiguous global reads. Mask: 1 b128/lane from packed layout.
// P transform: wave-private LDS (stride 40). Reg-prefetch next step's tiles.
// ---------------------------------------------------------------------------
__global__ __launch_bounds__(256) void attn_kernel(
    const unsigned short* __restrict__ Q, const unsigned short* __restrict__ K,
    const unsigned short* __restrict__ Vp, const unsigned short* __restrict__ maskP,
    unsigned short* __restrict__ AO)
{
  __shared__ __align__(16) unsigned short kt[32 * 72];     // [s_local][d]
  __shared__ __align__(16) unsigned short vt[64 * 40];     // [d][s_local]
  __shared__ __align__(16) unsigned short pt[4][16 * 40];  // per-wave P

  int tid = threadIdx.x, wv = tid >> 6, lane = tid & 63;
  int li = lane & 15, g = lane >> 4;
  int bh = blockIdx.x >> 5;
  int q0 = (blockIdx.x & 31) * 64 + wv * 16;

  const unsigned short* Qbase = Q + ((size_t)bh * SS + q0 + li) * 64;
  short8 qf0 = *(const short8*)(Qbase + g * 8);
  short8 qf1 = *(const short8*)(Qbase + 32 + g * 8);

  const unsigned short* Kg = K + (size_t)bh * SS * 64 + (tid >> 3) * 64 + (tid & 7) * 8;
  const unsigned short* Vg = Vp + (size_t)bh * 131072 + tid * 8;
  const unsigned short* Mg = maskP + (size_t)(q0 >> 4) * 64 * 512 + lane * 8;

  int kldsoff = (tid >> 3) * 72 + (tid & 7) * 8;
  int vldsoff = (tid >> 2) * 40 + (tid & 3) * 8;

  float4v acc_o[4] = {{0,0,0,0},{0,0,0,0},{0,0,0,0},{0,0,0,0}};
  float den[4] = {0.f, 0.f, 0.f, 0.f};
  unsigned short* myp = pt[wv];

  short8 kreg = *(const short8*)Kg;
  short8 vreg = *(const short8*)Vg;
  ushort8 mcur = *(const ushort8*)Mg;

  for (int step = 0; step < 64; ++step) {
    __syncthreads();                        // prior step's LDS reads done
    *(short8*)(kt + kldsoff) = kreg;
    *(short8*)(vt + vldsoff) = vreg;
    int ns = (step + 1 < 64) ? step + 1 : 0;  // redundant tail prefetch
    kreg = *(const short8*)(Kg + (size_t)ns * 2048);
    vreg = *(const short8*)(Vg + (size_t)ns * 2048);
    ushort8 mnxt = *(const ushort8*)(Mg + (size_t)ns * 512);
    __syncthreads();                        // tiles ready

    float4v pa[2];
#pragma unroll
    for (int sb = 0; sb < 2; ++sb) {
      short8 k0 = *(const short8*)(kt + (sb * 16 + li) * 72 + g * 8);
      short8 k1 = *(const short8*)(kt + (sb * 16 + li) * 72 + 32 + g * 8);
      float4v a = {0, 0, 0, 0};
      a = __builtin_amdgcn_mfma_f32_16x16x32_bf16(qf0, k0, a, 0, 0, 0);
      a = __builtin_amdgcn_mfma_f32_16x16x32_bf16(qf1, k1, a, 0, 0, 0);
      pa[sb] = a;
    }
#pragma unroll
    for (int sb = 0; sb < 2; ++sb)
#pragma unroll
      for (int r = 0; r < 4; ++r) {
        float p = __builtin_amdgcn_exp2f(pa[sb][r] * bf2f(mcur[sb * 4 + r]));
        den[r] += p;
        myp[(g * 4 + r) * 40 + sb * 16 + li] = f2bf(p);
      }
    asm volatile("s_waitcnt lgkmcnt(0)" ::: "memory");
    short8 pf = *(const short8*)(myp + li * 40 + g * 8);
#pragma unroll
    for (int nb = 0; nb < 4; ++nb) {
      short8 vf = *(const short8*)(vt + (nb * 16 + li) * 40 + g * 8);
      acc_o[nb] = __builtin_amdgcn_mfma_f32_16x16x32_bf16(pf, vf, acc_o[nb], 0, 0, 0);
    }
    mcur = mnxt;
  }

#pragma unroll
  for (int r = 0; r < 4; ++r) {
    den[r] += __shfl_xor(den[r], 1, 64);
    den[r] += __shfl_xor(den[r], 2, 64);
    den[r] += __shfl_xor(den[r], 4, 64);
    den[r] += __shfl_xor(den[r], 8, 64);
  }

  int b = bh >> 4, h = bh & 15;
#pragma unroll
  for (int nb = 0; nb < 4; ++nb)
#pragma unroll
    for (int r = 0; r < 4; ++r) {
      float o = acc_o[nb][r] / den[r];
      int s = q0 + g * 4 + r;
      AO[((size_t)(b * SS + s)) * EE + h * 64 + nb * 16 + li] = f2bf(o);
    }
}

// ---------------------------------------------------------------------------
// Kernel E: out = AO(4096x1024 bf16) @ Wo(fp32) + bo. LDS-staged 64x64 tiles,
// BK=64, Wo transposed+converted during staging (transpose_wo eliminated).
// ---------------------------------------------------------------------------
__global__ __launch_bounds__(256) void out_gemm(
    const unsigned short* __restrict__ AO, const float* __restrict__ Wo,
    const float* __restrict__ bo, float* __restrict__ out)
{
  __shared__ __align__(16) unsigned short at[64 * 72];   // [m][k]
  __shared__ __align__(16) unsigned short bt[64 * 72];   // [n][k]
  int tid = threadIdx.x, wv = tid >> 6, lane = tid & 63;
  int li = lane & 15, g = lane >> 4;
  int m0 = (blockIdx.x >> 4) * 64;
  int n0 = (blockIdx.x & 15) * 64;

  const unsigned short* Ag = AO + (size_t)m0 * 1024;
  const float* Bg = Wo + n0;

  short8 areg[2];
  float4 breg[4];

  auto loadA = [&](int k0) {
#pragma unroll
    for (int i = 0; i < 2; ++i) {
      int flat = tid + i * 256;              // row = flat>>3, c = flat&7
      areg[i] = *(const short8*)(Ag + (size_t)(flat >> 3) * 1024 + k0 + (flat & 7) * 8);
    }
  };
  auto loadB = [&](int k0) {
#pragma unroll
    for (int i = 0; i < 4; ++i) {
      int flat = tid + i * 256;              // krow = flat>>4, ch = flat&15
      breg[i] = *(const float4*)(Bg + (size_t)(k0 + (flat >> 4)) * 1024 + (flat & 15) * 4);
    }
  };

  float4v acc[4] = {{0,0,0,0},{0,0,0,0},{0,0,0,0},{0,0,0,0}};
  loadA(0); loadB(0);
  for (int k0 = 0; k0 < 1024; k0 += 64) {
    __syncthreads();
#pragma unroll
    for (int i = 0; i < 2; ++i) {
      int flat = tid + i * 256;
      *(short8*)(at + (flat >> 3) * 72 + (flat & 7) * 8) = areg[i];
    }
#pragma unroll
    for (int i = 0; i < 4; ++i) {
      int flat = tid + i * 256;
      int krow = flat >> 4, ch = flat & 15;
      float4 v = breg[i];
      bt[(ch * 4 + 0) * 72 + krow] = f2bf(v.x);
      bt[(ch * 4 + 1) * 72 + krow] = f2bf(v.y);
      bt[(ch * 4 + 2) * 72 + krow] = f2bf(v.z);
      bt[(ch * 4 + 3) * 72 + krow] = f2bf(v.w);
    }
    int nk = (k0 + 64 < 1024) ? k0 + 64 : 0;
    loadA(nk); loadB(nk);
    __syncthreads();
#pragma unroll
    for (int ks = 0; ks < 2; ++ks) {
      short8 af = *(const short8*)(at + (wv * 16 + li) * 72 + ks * 32 + g * 8);
#pragma unroll
      for (int nb = 0; nb < 4; ++nb) {
        short8 bfr = *(const short8*)(bt + (nb * 16 + li) * 72 + ks * 32 + g * 8);
        acc[nb] = __builtin_amdgcn_mfma_f32_16x16x32_bf16(af, bfr, acc[nb], 0, 0, 0);
      }
    }
  }
#pragma unroll
  for (int nb = 0; nb < 4; ++nb) {
    float bof = bo[n0 + nb * 16 + li];
#pragma unroll
    for (int r = 0; r < 4; ++r)
      out[(size_t)(m0 + wv * 16 + g * 4 + r) * 1024 + n0 + nb * 16 + li] = acc[nb][r] + bof;
  }
}

// ---------------------------------------------------------------------------
extern "C" void kernel_launch(void* const* d_in, const int* in_sizes, int n_in,
                              void* d_out, int out_size, void* d_ws, size_t ws_size,
                              hipStream_t stream) {
  const float* x    = (const float*)d_in[0];
  const float* mask = (const float*)d_in[1];
  const float* Wq   = (const float*)d_in[2];
  const float* bq   = (const float*)d_in[3];
  const float* Wk   = (const float*)d_in[4];
  const float* bk   = (const float*)d_in[5];
  const float* Wv   = (const float*)d_in[6];
  const float* bv   = (const float*)d_in[7];
  const float* Wo   = (const float*)d_in[8];
  const float* bo   = (const float*)d_in[9];
  float* out = (float*)d_out;

  unsigned short* ws = (unsigned short*)d_ws;
  unsigned short* Q     = ws;                 // 4M ushort each
  unsigned short* K     = ws + 4194304;
  unsigned short* Vp    = ws + 8388608;
  unsigned short* AO    = ws + 12582912;
  unsigned short* maskP = ws + 16777216;      // 4M

  qkv_kernel<<<1024, 256, 0, stream>>>(x, Wq, bq, Wk, bk, Wv, bv, Q, K, Vp);
  mask_prep<<<2048, 256, 0, stream>>>(mask, maskP);
  attn_kernel<<<1024, 256, 0, stream>>>(Q, K, Vp, maskP, AO);
  out_gemm<<<1024, 256, 0, stream>>>(AO, Wo, bo, out);
}

// Round 5
// 202.606 us; speedup vs baseline: 2.4955x; 1.1445x over previous
//
#include <hip/hip_runtime.h>
#include <hip/hip_bf16.h>

// B=2, S=2048, E=1024, H=16, HD=KD=VD=64. fp32 I/O, bf16 MFMA internals.
#define SS 2048
#define EE 1024
#define SCALE 0.125f
#define LOG2E 1.44269504088896f

typedef __attribute__((ext_vector_type(8))) short short8;
typedef __attribute__((ext_vector_type(4))) float float4v;
typedef __attribute__((ext_vector_type(8))) unsigned short ushort8;

__device__ __forceinline__ float bf2f(unsigned short u) {
  unsigned int v = ((unsigned int)u) << 16;
  return __uint_as_float(v);
}
__device__ __forceinline__ unsigned short f2bf(float f) {
  unsigned int u = __float_as_uint(f);
  unsigned int lsb = (u >> 16) & 1u;
  u += 0x7fffu + lsb;           // RNE
  return (unsigned short)(u >> 16);
}
__device__ __forceinline__ unsigned int pk2bf(float a, float b) {
  __hip_bfloat162 h = __float22bfloat162_rn(float2{a, b});
  return *reinterpret_cast<unsigned int*>(&h);
}

// ---------------------------------------------------------------------------
// Kernel 0: W3T[n'][d] bf16, n' = mtx*64+n, from Wq/Wk/Wv fp32 [d][n]. 3 blocks.
// ---------------------------------------------------------------------------
__global__ __launch_bounds__(256) void w3t_prep(
    const float* __restrict__ Wq, const float* __restrict__ Wk,
    const float* __restrict__ Wv, unsigned short* __restrict__ W3T)
{
  __shared__ unsigned short t[64 * 65];
  const float* W = (blockIdx.x == 0) ? Wq : (blockIdx.x == 1 ? Wk : Wv);
  int tid = threadIdx.x;
#pragma unroll
  for (int i = 0; i < 16; ++i) {
    int e = tid + i * 256; int d = e >> 6, n = e & 63;
    t[n * 65 + d] = f2bf(W[e]);
  }
  __syncthreads();
  unsigned short* dst = W3T + blockIdx.x * 4096;
#pragma unroll
  for (int i = 0; i < 16; ++i) {
    int e = tid + i * 256; int n = e >> 6, d = e & 63;
    dst[n * 64 + d] = t[n * 65 + d];
  }
}

// ---------------------------------------------------------------------------
// Kernel 1: QKV projection MFMA GEMM. Block = 64 s-rows of one bh, 4 waves.
// W3T staged 24KB via b128; x staged fp32->bf16. V written pos-permuted:
// Vp[bh][s/32][d][pos], pos = (s&15)*2 + ((s>>4)&1)  (k-order for PV MFMA).
// ---------------------------------------------------------------------------
__global__ __launch_bounds__(256) void qkv_kernel(
    const float* __restrict__ x, const unsigned short* __restrict__ W3T,
    const float* __restrict__ bq, const float* __restrict__ bk,
    const float* __restrict__ bv,
    unsigned short* __restrict__ Q, unsigned short* __restrict__ K,
    unsigned short* __restrict__ Vp)
{
  __shared__ __align__(16) unsigned short w3t[192 * 72];
  __shared__ __align__(16) unsigned short xt[64 * 72];
  __shared__ float sBias[192];
  int tid = threadIdx.x;
  int bh = blockIdx.x >> 5;
  int s0blk = (blockIdx.x & 31) * 64;
  int b = bh >> 4, h = bh & 15;

#pragma unroll
  for (int i = 0; i < 6; ++i) {
    int slot = tid + i * 256;
    int row = slot >> 3, c = slot & 7;
    *(short8*)(w3t + row * 72 + c * 8) = *(const short8*)(W3T + slot * 8);
  }
  if (tid < 192) sBias[tid] = (tid < 64) ? bq[tid] : (tid < 128 ? bk[tid - 64] : bv[tid - 128]);

  const float* xbase = x + ((size_t)(b * SS + s0blk)) * EE + h * 64;
#pragma unroll
  for (int it = 0; it < 4; ++it) {
    int flat = tid + it * 256;
    int row = flat >> 4, ch = flat & 15;
    float4 v = *(const float4*)(xbase + (size_t)row * EE + ch * 4);
    uint2 u; u.x = pk2bf(v.x, v.y); u.y = pk2bf(v.z, v.w);
    *(uint2*)(xt + row * 72 + ch * 4) = u;
  }
  __syncthreads();

  int wv = tid >> 6, lane = tid & 63;
  int li = lane & 15, g = lane >> 4;
  int mrow = wv * 16;

  short8 af[2];
#pragma unroll
  for (int ks = 0; ks < 2; ++ks)
    af[ks] = *(const short8*)(xt + (mrow + li) * 72 + ks * 32 + g * 8);

  float4v acc[12];
#pragma unroll
  for (int i = 0; i < 12; ++i) acc[i] = (float4v){0, 0, 0, 0};
#pragma unroll
  for (int ks = 0; ks < 2; ++ks)
#pragma unroll
    for (int nb = 0; nb < 12; ++nb) {
      short8 bfr = *(const short8*)(w3t + (nb * 16 + li) * 72 + ks * 32 + g * 8);
      acc[nb] = __builtin_amdgcn_mfma_f32_16x16x32_bf16(af[ks], bfr, acc[nb], 0, 0, 0);
    }

  int srow0 = s0blk + mrow + g * 4;
#pragma unroll
  for (int nb = 0; nb < 12; ++nb) {
    float bias = sBias[nb * 16 + li];
    int mtx = nb >> 2, sub = nb & 3;
#pragma unroll
    for (int r = 0; r < 4; ++r) {
      unsigned short ob = f2bf(acc[nb][r] + bias);
      int s = srow0 + r;
      if (mtx == 0)      Q[((size_t)bh * SS + s) * 64 + sub * 16 + li] = ob;
      else if (mtx == 1) K[((size_t)bh * SS + s) * 64 + sub * 16 + li] = ob;
      else {
        int sl = s & 31;
        int pos = ((sl & 15) << 1) | (sl >> 4);
        Vp[(size_t)bh * 131072 + (size_t)(s >> 5) * 2048 + (sub * 16 + li) * 32 + pos] = ob;
      }
    }
  }
}

// ---------------------------------------------------------------------------
// Kernel 2: pack mask into per-lane fragment order, folding SCALE*log2(e).
// maskP[(qt*64+t)*512 + lane*8 + sb*4 + r] = bf16(mask[qt*16+g*4+r][t*32+sb*16+li]*c)
// ---------------------------------------------------------------------------
__global__ __launch_bounds__(256) void mask_prep(
    const float* __restrict__ mask, unsigned short* __restrict__ maskP)
{
  int idx = blockIdx.x * 256 + threadIdx.x;
  int lane = idx & 63, t = (idx >> 6) & 63, qt = idx >> 12;
  int li = lane & 15, g = lane >> 4;
  const float c = SCALE * LOG2E;
  ushort8 o;
#pragma unroll
  for (int sb = 0; sb < 2; ++sb)
#pragma unroll
    for (int r = 0; r < 4; ++r)
      o[sb * 4 + r] = f2bf(mask[(size_t)(qt * 16 + g * 4 + r) * SS + t * 32 + sb * 16 + li] * c);
  *(ushort8*)(maskP + (size_t)idx * 8) = o;
}

// ---------------------------------------------------------------------------
// Kernel 3: flash attention. Block = 128 q-rows of one bh (4 waves x 32 q).
// K/V tiles LDS-staged (b128, audited strides); P transform uses the
// pos-permuted k-order: write packed b32 pairs, read b128 A-frags.
// ---------------------------------------------------------------------------
__global__ __launch_bounds__(256) void attn_kernel(
    const unsigned short* __restrict__ Q, const unsigned short* __restrict__ K,
    const unsigned short* __restrict__ Vp, const unsigned short* __restrict__ maskP,
    unsigned short* __restrict__ AO)
{
  __shared__ __align__(16) unsigned short kt[32 * 88];       // [s][d] stride 88
  __shared__ __align__(16) unsigned short vt[64 * 40];       // [d][pos] stride 40
  __shared__ __align__(16) unsigned short pt[4][2][16 * 40]; // [wave][tile][q][pos]

  int tid = threadIdx.x, wv = tid >> 6, lane = tid & 63;
  int li = lane & 15, g = lane >> 4;
  int bh = blockIdx.x >> 4;
  int q0 = (blockIdx.x & 15) * 128 + wv * 32;

  const unsigned short* Qb0 = Q + ((size_t)bh * SS + q0 + li) * 64;
  const unsigned short* Qb1 = Q + ((size_t)bh * SS + q0 + 16 + li) * 64;
  short8 qf[2][2];
  qf[0][0] = *(const short8*)(Qb0 + g * 8);
  qf[0][1] = *(const short8*)(Qb0 + 32 + g * 8);
  qf[1][0] = *(const short8*)(Qb1 + g * 8);
  qf[1][1] = *(const short8*)(Qb1 + 32 + g * 8);

  const unsigned short* Kg = K + (size_t)bh * SS * 64 + tid * 8;
  const unsigned short* Vg = Vp + (size_t)bh * 131072 + tid * 8;
  const unsigned short* Mg0 = maskP + (size_t)(q0 >> 4) * 32768 + lane * 8;
  const unsigned short* Mg1 = Mg0 + 32768;

  int kldso = (tid >> 3) * 88 + (tid & 7) * 8;
  int vldso = (tid >> 2) * 40 + (tid & 3) * 8;

  float4v acc[2][4];
#pragma unroll
  for (int t = 0; t < 2; ++t)
#pragma unroll
    for (int nb = 0; nb < 4; ++nb) acc[t][nb] = (float4v){0, 0, 0, 0};
  float den[2][4] = {{0, 0, 0, 0}, {0, 0, 0, 0}};
  unsigned short* ptb[2] = {pt[wv][0], pt[wv][1]};

  short8 kreg = *(const short8*)Kg;
  short8 vreg = *(const short8*)Vg;
  ushort8 mc[2];
  mc[0] = *(const ushort8*)Mg0;
  mc[1] = *(const ushort8*)Mg1;

  for (int step = 0; step < 64; ++step) {
    __syncthreads();                         // prior-step LDS reads done
    *(short8*)(kt + kldso) = kreg;
    *(short8*)(vt + vldso) = vreg;
    int ns = (step + 1 < 64) ? step + 1 : 0;
    kreg = *(const short8*)(Kg + (size_t)ns * 2048);
    vreg = *(const short8*)(Vg + (size_t)ns * 2048);
    ushort8 mn0 = *(const ushort8*)(Mg0 + (size_t)ns * 512);
    ushort8 mn1 = *(const ushort8*)(Mg1 + (size_t)ns * 512);
    __syncthreads();                         // tiles ready

    short8 kf[2][2];
#pragma unroll
    for (int sb = 0; sb < 2; ++sb) {
      kf[sb][0] = *(const short8*)(kt + (sb * 16 + li) * 88 + g * 8);
      kf[sb][1] = *(const short8*)(kt + (sb * 16 + li) * 88 + 32 + g * 8);
    }
#pragma unroll
    for (int t = 0; t < 2; ++t) {
      float4v pa0 = {0, 0, 0, 0}, pa1 = {0, 0, 0, 0};
      pa0 = __builtin_amdgcn_mfma_f32_16x16x32_bf16(qf[t][0], kf[0][0], pa0, 0, 0, 0);
      pa0 = __builtin_amdgcn_mfma_f32_16x16x32_bf16(qf[t][1], kf[0][1], pa0, 0, 0, 0);
      pa1 = __builtin_amdgcn_mfma_f32_16x16x32_bf16(qf[t][0], kf[1][0], pa1, 0, 0, 0);
      pa1 = __builtin_amdgcn_mfma_f32_16x16x32_bf16(qf[t][1], kf[1][1], pa1, 0, 0, 0);
#pragma unroll
      for (int r = 0; r < 4; ++r) {
        float p0 = __builtin_amdgcn_exp2f(pa0[r] * bf2f(mc[t][r]));
        float p1 = __builtin_amdgcn_exp2f(pa1[r] * bf2f(mc[t][4 + r]));
        den[t][r] += p0 + p1;
        *(unsigned int*)(ptb[t] + (g * 4 + r) * 40 + li * 2) = pk2bf(p0, p1);
      }
    }
    asm volatile("s_waitcnt lgkmcnt(0)" ::: "memory");
    short8 pf0 = *(const short8*)(ptb[0] + li * 40 + g * 8);
    short8 pf1 = *(const short8*)(ptb[1] + li * 40 + g * 8);
#pragma unroll
    for (int nb = 0; nb < 4; ++nb) {
      short8 vf = *(const short8*)(vt + (nb * 16 + li) * 40 + g * 8);
      acc[0][nb] = __builtin_amdgcn_mfma_f32_16x16x32_bf16(pf0, vf, acc[0][nb], 0, 0, 0);
      acc[1][nb] = __builtin_amdgcn_mfma_f32_16x16x32_bf16(pf1, vf, acc[1][nb], 0, 0, 0);
    }
    mc[0] = mn0; mc[1] = mn1;
  }

#pragma unroll
  for (int t = 0; t < 2; ++t)
#pragma unroll
    for (int r = 0; r < 4; ++r) {
      den[t][r] += __shfl_xor(den[t][r], 1, 64);
      den[t][r] += __shfl_xor(den[t][r], 2, 64);
      den[t][r] += __shfl_xor(den[t][r], 4, 64);
      den[t][r] += __shfl_xor(den[t][r], 8, 64);
    }

  int b = bh >> 4, h = bh & 15;
#pragma unroll
  for (int t = 0; t < 2; ++t)
#pragma unroll
    for (int nb = 0; nb < 4; ++nb)
#pragma unroll
      for (int r = 0; r < 4; ++r) {
        float o = acc[t][nb][r] / den[t][r];
        int s = q0 + t * 16 + g * 4 + r;
        AO[((size_t)(b * SS + s)) * EE + h * 64 + nb * 16 + li] = f2bf(o);
      }
}

// ---------------------------------------------------------------------------
// Kernel 4: transpose Wo (fp32 [k][n]) -> WoT (bf16 [n][k]). Runs after attn
// (WoT aliases maskP region).
// ---------------------------------------------------------------------------
__global__ __launch_bounds__(256) void transpose_wo(
    const float* __restrict__ Wo, unsigned short* __restrict__ WoT)
{
  __shared__ unsigned short t[64 * 65];
  int tid = threadIdx.x;
  int k0 = (blockIdx.x >> 4) * 64;
  int n0 = (blockIdx.x & 15) * 64;
#pragma unroll
  for (int i = 0; i < 16; ++i) {
    int idx = tid + i * 256;
    int k = idx >> 6, n = idx & 63;
    t[n * 65 + k] = f2bf(Wo[(size_t)(k0 + k) * 1024 + n0 + n]);
  }
  __syncthreads();
#pragma unroll
  for (int i = 0; i < 16; ++i) {
    int idx = tid + i * 256;
    int n = idx >> 6, k = idx & 63;
    WoT[(size_t)(n0 + n) * 1024 + k0 + k] = t[n * 65 + k];
  }
}

// ---------------------------------------------------------------------------
// Kernel 5: out = AO(4096x1024 bf16) @ WoT^T + bo. 128x128 tile, BK=64,
// 4 waves of 64x64; all staging b128; reg-prefetch next K-slab.
// ---------------------------------------------------------------------------
__global__ __launch_bounds__(256) void out_gemm(
    const unsigned short* __restrict__ AO, const unsigned short* __restrict__ WoT,
    const float* __restrict__ bo, float* __restrict__ out)
{
  __shared__ __align__(16) unsigned short at[128 * 72];
  __shared__ __align__(16) unsigned short btl[128 * 72];
  int tid = threadIdx.x, wv = tid >> 6, lane = tid & 63;
  int li = lane & 15, g = lane >> 4;
  int m0 = (blockIdx.x >> 3) * 128;
  int n0 = (blockIdx.x & 7) * 128;
  int wm = (wv & 1) * 64, wn = (wv >> 1) * 64;

  const unsigned short* Ag = AO + (size_t)m0 * 1024;
  const unsigned short* Bg = WoT + (size_t)n0 * 1024;

  short8 apre[4], bpre[4];
  int srow = tid >> 3, scol = (tid & 7) * 8;

  auto ldst = [&](int k0) {
#pragma unroll
    for (int i = 0; i < 4; ++i) {
      apre[i] = *(const short8*)(Ag + (size_t)(srow + i * 32) * 1024 + k0 + scol);
      bpre[i] = *(const short8*)(Bg + (size_t)(srow + i * 32) * 1024 + k0 + scol);
    }
  };

  float4v acc[4][4];
#pragma unroll
  for (int mt = 0; mt < 4; ++mt)
#pragma unroll
    for (int nt = 0; nt < 4; ++nt) acc[mt][nt] = (float4v){0, 0, 0, 0};

  ldst(0);
  for (int k0 = 0; k0 < 1024; k0 += 64) {
    __syncthreads();
#pragma unroll
    for (int i = 0; i < 4; ++i) {
      *(short8*)(at + (srow + i * 32) * 72 + scol) = apre[i];
      *(short8*)(btl + (srow + i * 32) * 72 + scol) = bpre[i];
    }
    int nk = (k0 + 64 < 1024) ? k0 + 64 : 0;
    ldst(nk);
    __syncthreads();
#pragma unroll
    for (int ks = 0; ks < 2; ++ks) {
      short8 afr[4], bfr[4];
#pragma unroll
      for (int mt = 0; mt < 4; ++mt)
        afr[mt] = *(const short8*)(at + (wm + mt * 16 + li) * 72 + ks * 32 + g * 8);
#pragma unroll
      for (int nt = 0; nt < 4; ++nt)
        bfr[nt] = *(const short8*)(btl + (wn + nt * 16 + li) * 72 + ks * 32 + g * 8);
#pragma unroll
      for (int mt = 0; mt < 4; ++mt)
#pragma unroll
        for (int nt = 0; nt < 4; ++nt)
          acc[mt][nt] = __builtin_amdgcn_mfma_f32_16x16x32_bf16(afr[mt], bfr[nt], acc[mt][nt], 0, 0, 0);
    }
  }
#pragma unroll
  for (int nt = 0; nt < 4; ++nt) {
    float bof = bo[n0 + wn + nt * 16 + li];
#pragma unroll
    for (int mt = 0; mt < 4; ++mt)
#pragma unroll
      for (int r = 0; r < 4; ++r)
        out[(size_t)(m0 + wm + mt * 16 + g * 4 + r) * 1024 + n0 + wn + nt * 16 + li] =
            acc[mt][nt][r] + bof;
  }
}

// ---------------------------------------------------------------------------
extern "C" void kernel_launch(void* const* d_in, const int* in_sizes, int n_in,
                              void* d_out, int out_size, void* d_ws, size_t ws_size,
                              hipStream_t stream) {
  const float* x    = (const float*)d_in[0];
  const float* mask = (const float*)d_in[1];
  const float* Wq   = (const float*)d_in[2];
  const float* bq   = (const float*)d_in[3];
  const float* Wk   = (const float*)d_in[4];
  const float* bk   = (const float*)d_in[5];
  const float* Wv   = (const float*)d_in[6];
  const float* bv   = (const float*)d_in[7];
  const float* Wo   = (const float*)d_in[8];
  const float* bo   = (const float*)d_in[9];
  float* out = (float*)d_out;

  unsigned short* ws = (unsigned short*)d_ws;
  unsigned short* Q     = ws;                 // 4M ushort regions
  unsigned short* K     = ws + 4194304;
  unsigned short* Vp    = ws + 8388608;
  unsigned short* AO    = ws + 12582912;
  unsigned short* maskP = ws + 16777216;
  // time-aliased: W3T lives in AO region (dead until attn writes AO);
  // WoT lives in maskP region (dead after attn reads maskP).
  unsigned short* W3T = AO;
  unsigned short* WoT = maskP;

  w3t_prep<<<3, 256, 0, stream>>>(Wq, Wk, Wv, W3T);
  qkv_kernel<<<1024, 256, 0, stream>>>(x, W3T, bq, bk, bv, Q, K, Vp);
  mask_prep<<<2048, 256, 0, stream>>>(mask, maskP);
  attn_kernel<<<512, 256, 0, stream>>>(Q, K, Vp, maskP, AO);
  transpose_wo<<<256, 256, 0, stream>>>(Wo, WoT);
  out_gemm<<<256, 256, 0, stream>>>(AO, WoT, bo, out);
}

// Round 6
// 188.686 us; speedup vs baseline: 2.6796x; 1.0738x over previous
//
#include <hip/hip_runtime.h>
#include <hip/hip_bf16.h>

// B=2, S=2048, E=1024, H=16, HD=KD=VD=64. fp32 I/O, bf16 MFMA internals.
// R6: S^T formulation — P^T stays in registers as PV B-fragment (shared
// k-permutation with packed V). No per-step P LDS round-trip; 1 barrier/step.
#define SS 2048
#define EE 1024
#define SCALE 0.125f
#define LOG2E 1.44269504088896f

typedef __attribute__((ext_vector_type(8))) short short8;
typedef __attribute__((ext_vector_type(4))) float float4v;
typedef __attribute__((ext_vector_type(8))) unsigned short ushort8;
typedef __attribute__((ext_vector_type(4))) unsigned int uint4v;

__device__ __forceinline__ float bf2f(unsigned short u) {
  unsigned int v = ((unsigned int)u) << 16;
  return __uint_as_float(v);
}
__device__ __forceinline__ unsigned short f2bf(float f) {
  unsigned int u = __float_as_uint(f);
  unsigned int lsb = (u >> 16) & 1u;
  u += 0x7fffu + lsb;           // RNE
  return (unsigned short)(u >> 16);
}
__device__ __forceinline__ unsigned int pk2bf(float a, float b) {
  __hip_bfloat162 h = __float22bfloat162_rn(float2{a, b});
  return *reinterpret_cast<unsigned int*>(&h);
}

// ---------------------------------------------------------------------------
// Kernel 0: W3T[n'][d] bf16, n' = mtx*64+n, from Wq/Wk/Wv fp32 [d][n].
// ---------------------------------------------------------------------------
__global__ __launch_bounds__(256) void w3t_prep(
    const float* __restrict__ Wq, const float* __restrict__ Wk,
    const float* __restrict__ Wv, unsigned short* __restrict__ W3T)
{
  __shared__ unsigned short t[64 * 65];
  const float* W = (blockIdx.x == 0) ? Wq : (blockIdx.x == 1 ? Wk : Wv);
  int tid = threadIdx.x;
#pragma unroll
  for (int i = 0; i < 16; ++i) {
    int e = tid + i * 256; int d = e >> 6, n = e & 63;
    t[n * 65 + d] = f2bf(W[e]);
  }
  __syncthreads();
  unsigned short* dst = W3T + blockIdx.x * 4096;
#pragma unroll
  for (int i = 0; i < 16; ++i) {
    int e = tid + i * 256; int n = e >> 6, d = e & 63;
    dst[n * 64 + d] = t[n * 65 + d];
  }
}

// ---------------------------------------------------------------------------
// Kernel 1: QKV projection MFMA GEMM. Block = 128 s-rows of one bh (2 slabs
// of 64), W3T staged once per block. V written with the PV k-permutation:
// Vp[bh][s/32][d][pos], pos = ((s>>2)&3)*8 + ((s>>4)&1)*4 + (s&3).
// ---------------------------------------------------------------------------
__global__ __launch_bounds__(256) void qkv_kernel(
    const float* __restrict__ x, const unsigned short* __restrict__ W3T,
    const float* __restrict__ bq, const float* __restrict__ bk,
    const float* __restrict__ bv,
    unsigned short* __restrict__ Q, unsigned short* __restrict__ K,
    unsigned short* __restrict__ Vp)
{
  __shared__ __align__(16) unsigned short w3t[192 * 72];
  __shared__ __align__(16) unsigned short xt[64 * 72];
  __shared__ float sBias[192];
  int tid = threadIdx.x;
  int bh = blockIdx.x >> 4;
  int s0blk = (blockIdx.x & 15) * 128;
  int b = bh >> 4, h = bh & 15;
  int wv = tid >> 6, lane = tid & 63;
  int li = lane & 15, g = lane >> 4;

#pragma unroll
  for (int i = 0; i < 6; ++i) {
    int slot = tid + i * 256;
    int row = slot >> 3, c = slot & 7;
    *(short8*)(w3t + row * 72 + c * 8) = *(const short8*)(W3T + slot * 8);
  }
  if (tid < 192) sBias[tid] = (tid < 64) ? bq[tid] : (tid < 128 ? bk[tid - 64] : bv[tid - 128]);

  for (int half = 0; half < 2; ++half) {
    int s0 = s0blk + half * 64;
    if (half) __syncthreads();          // prior frag reads done before restage
    const float* xbase = x + ((size_t)(b * SS + s0)) * EE + h * 64;
#pragma unroll
    for (int it = 0; it < 4; ++it) {
      int flat = tid + it * 256;
      int row = flat >> 4, ch = flat & 15;
      float4 v = *(const float4*)(xbase + (size_t)row * EE + ch * 4);
      uint2 u; u.x = pk2bf(v.x, v.y); u.y = pk2bf(v.z, v.w);
      *(uint2*)(xt + row * 72 + ch * 4) = u;
    }
    __syncthreads();

    int mrow = wv * 16;
    short8 af[2];
#pragma unroll
    for (int ks = 0; ks < 2; ++ks)
      af[ks] = *(const short8*)(xt + (mrow + li) * 72 + ks * 32 + g * 8);

    float4v acc[12];
#pragma unroll
    for (int i = 0; i < 12; ++i) acc[i] = (float4v){0, 0, 0, 0};
#pragma unroll
    for (int ks = 0; ks < 2; ++ks)
#pragma unroll
      for (int nb = 0; nb < 12; ++nb) {
        short8 bfr = *(const short8*)(w3t + (nb * 16 + li) * 72 + ks * 32 + g * 8);
        acc[nb] = __builtin_amdgcn_mfma_f32_16x16x32_bf16(af[ks], bfr, acc[nb], 0, 0, 0);
      }

    int srow0 = s0 + mrow + g * 4;
#pragma unroll
    for (int nb = 0; nb < 12; ++nb) {
      float bias = sBias[nb * 16 + li];
      int mtx = nb >> 2, sub = nb & 3;
#pragma unroll
      for (int r = 0; r < 4; ++r) {
        unsigned short ob = f2bf(acc[nb][r] + bias);
        int s = srow0 + r;
        if (mtx == 0)      Q[((size_t)bh * SS + s) * 64 + sub * 16 + li] = ob;
        else if (mtx == 1) K[((size_t)bh * SS + s) * 64 + sub * 16 + li] = ob;
        else {
          int sl = s & 31;
          int pos = ((sl >> 2) & 3) * 8 + ((sl >> 4) & 1) * 4 + (sl & 3);
          Vp[(size_t)bh * 131072 + (size_t)(s >> 5) * 2048 + (sub * 16 + li) * 32 + pos] = ob;
        }
      }
    }
  }
}

// ---------------------------------------------------------------------------
// Kernel 2: pack mask in B-frag j-order, folding SCALE*log2(e).
// maskP[((qt*64+step)*64 + lane)*8 + j] =
//   bf16(c * mask[qt*16+li][step*32 + (j>>2)*16 + g*4 + (j&3)]),  lane=g*16+li.
// ---------------------------------------------------------------------------
__global__ __launch_bounds__(256) void mask_prep(
    const float* __restrict__ mask, unsigned short* __restrict__ maskP)
{
  int idx = blockIdx.x * 256 + threadIdx.x;
  int lane = idx & 63, step = (idx >> 6) & 63, qt = idx >> 12;
  int li = lane & 15, g = lane >> 4;
  const float c = SCALE * LOG2E;
  const float* mrow = mask + (size_t)(qt * 16 + li) * SS + step * 32 + g * 4;
  float4 a = *(const float4*)mrow;
  float4 bb = *(const float4*)(mrow + 16);
  uint4v o;
  o.x = pk2bf(a.x * c, a.y * c);
  o.y = pk2bf(a.z * c, a.w * c);
  o.z = pk2bf(bb.x * c, bb.y * c);
  o.w = pk2bf(bb.z * c, bb.w * c);
  *(uint4v*)(maskP + (size_t)idx * 8) = o;
}

// ---------------------------------------------------------------------------
// Kernel 3: flash attention, S^T formulation. Block = 128 q-rows of one bh
// (4 waves x 32 q). Double-buffered K/V LDS tiles, 1 barrier/step.
// QK: A=K rows, B=Q rows -> P^T in C/D (q=li, s=(g,r)) -> exp in-register ->
// PV: A=V^T (pos-permuted k), B=P^T. O^T transposed via LDS once at end.
// ---------------------------------------------------------------------------
__global__ __launch_bounds__(256) void attn_kernel(
    const unsigned short* __restrict__ Q, const unsigned short* __restrict__ K,
    const unsigned short* __restrict__ Vp, const unsigned short* __restrict__ maskP,
    unsigned short* __restrict__ AO)
{
  __shared__ __align__(16) unsigned short lds[2 * 2816 + 2 * 2560];
  unsigned short* ktb0 = lds;
  unsigned short* ktb1 = lds + 2816;
  unsigned short* vtb0 = lds + 5632;
  unsigned short* vtb1 = lds + 8192;

  int tid = threadIdx.x, wv = tid >> 6, lane = tid & 63;
  int li = lane & 15, g = lane >> 4;
  int bh = blockIdx.x >> 4;
  int q0 = (blockIdx.x & 15) * 128 + wv * 32;

  short8 qf[2][2];
#pragma unroll
  for (int t = 0; t < 2; ++t) {
    const unsigned short* Qb = Q + ((size_t)bh * SS + q0 + t * 16 + li) * 64;
    qf[t][0] = *(const short8*)(Qb + g * 8);
    qf[t][1] = *(const short8*)(Qb + 32 + g * 8);
  }

  const unsigned short* Kg = K + (size_t)bh * SS * 64 + tid * 8;
  const unsigned short* Vg = Vp + (size_t)bh * 131072 + tid * 8;
  const unsigned short* Mg0 = maskP + (size_t)(q0 >> 4) * 32768 + lane * 8;
  const unsigned short* Mg1 = Mg0 + 32768;
  int kldso = (tid >> 3) * 88 + (tid & 7) * 8;
  int vldso = (tid >> 2) * 40 + (tid & 3) * 8;

  float4v acc[2][4];
#pragma unroll
  for (int t = 0; t < 2; ++t)
#pragma unroll
    for (int nb = 0; nb < 4; ++nb) acc[t][nb] = (float4v){0, 0, 0, 0};
  float2 den2[2] = {{0.f, 0.f}, {0.f, 0.f}};

  short8 kreg = *(const short8*)Kg;
  short8 vreg = *(const short8*)Vg;
  uint4v mc[2];
  mc[0] = *(const uint4v*)Mg0;
  mc[1] = *(const uint4v*)Mg1;
  *(short8*)(ktb0 + kldso) = kreg;
  *(short8*)(vtb0 + vldso) = vreg;
  __syncthreads();

  for (int step = 0; step < 64; ++step) {
    const unsigned short* kt = (step & 1) ? ktb1 : ktb0;
    const unsigned short* vt = (step & 1) ? vtb1 : vtb0;
    unsigned short* ktn = (step & 1) ? ktb0 : ktb1;
    unsigned short* vtn = (step & 1) ? vtb0 : vtb1;
    int ns = (step + 1 < 64) ? step + 1 : 0;
    kreg = *(const short8*)(Kg + (size_t)ns * 2048);
    vreg = *(const short8*)(Vg + (size_t)ns * 2048);
    uint4v mn0 = *(const uint4v*)(Mg0 + (size_t)ns * 512);
    uint4v mn1 = *(const uint4v*)(Mg1 + (size_t)ns * 512);

    short8 kf[2][2];
#pragma unroll
    for (int sb = 0; sb < 2; ++sb) {
      kf[sb][0] = *(const short8*)(kt + (sb * 16 + li) * 88 + g * 8);
      kf[sb][1] = *(const short8*)(kt + (sb * 16 + li) * 88 + 32 + g * 8);
    }

    uint4v pw[2];
#pragma unroll
    for (int t = 0; t < 2; ++t) {
#pragma unroll
      for (int sb = 0; sb < 2; ++sb) {
        float4v st = {0, 0, 0, 0};
        st = __builtin_amdgcn_mfma_f32_16x16x32_bf16(kf[sb][0], qf[t][0], st, 0, 0, 0);
        st = __builtin_amdgcn_mfma_f32_16x16x32_bf16(kf[sb][1], qf[t][1], st, 0, 0, 0);
#pragma unroll
        for (int hh = 0; hh < 2; ++hh) {
          unsigned int mm = (t == 0) ? mc[0][sb * 2 + hh] : mc[1][sb * 2 + hh];
          float mlo = __uint_as_float(mm << 16);
          float mhi = __uint_as_float(mm & 0xffff0000u);
          float p0 = __builtin_amdgcn_exp2f(st[2 * hh] * mlo);
          float p1 = __builtin_amdgcn_exp2f(st[2 * hh + 1] * mhi);
          den2[t].x += p0;
          den2[t].y += p1;
          pw[t][sb * 2 + hh] = pk2bf(p0, p1);
        }
      }
    }
    short8 pf0 = *(short8*)&pw[0];
    short8 pf1 = *(short8*)&pw[1];
#pragma unroll
    for (int nb = 0; nb < 4; ++nb) {
      short8 vf = *(const short8*)(vt + (nb * 16 + li) * 40 + g * 8);
      acc[0][nb] = __builtin_amdgcn_mfma_f32_16x16x32_bf16(vf, pf0, acc[0][nb], 0, 0, 0);
      acc[1][nb] = __builtin_amdgcn_mfma_f32_16x16x32_bf16(vf, pf1, acc[1][nb], 0, 0, 0);
    }
    *(short8*)(ktn + kldso) = kreg;
    *(short8*)(vtn + vldso) = vreg;
    mc[0] = mn0; mc[1] = mn1;
    __syncthreads();
  }

  // den reduce over g-groups (q lives at li), then O^T -> O via one LDS pass
  float rd[2];
#pragma unroll
  for (int t = 0; t < 2; ++t) {
    float d = den2[t].x + den2[t].y;
    d += __shfl_xor(d, 16, 64);
    d += __shfl_xor(d, 32, 64);
    rd[t] = 1.0f / d;
  }

  unsigned short* tr = lds + wv * 2304;   // 32 rows x 72 (aliases kt/vt)
#pragma unroll
  for (int t = 0; t < 2; ++t)
#pragma unroll
    for (int nb = 0; nb < 4; ++nb) {
      int base = (t * 16 + li) * 72 + nb * 16 + g * 4;
      *(unsigned int*)(tr + base)     = pk2bf(acc[t][nb][0] * rd[t], acc[t][nb][1] * rd[t]);
      *(unsigned int*)(tr + base + 2) = pk2bf(acc[t][nb][2] * rd[t], acc[t][nb][3] * rd[t]);
    }
  asm volatile("s_waitcnt lgkmcnt(0)" ::: "memory");

  int b = bh >> 4, h = bh & 15;
  int rrow = lane >> 3, part = lane & 7;
#pragma unroll
  for (int i = 0; i < 4; ++i) {
    int row = i * 8 + rrow;
    short8 ov = *(const short8*)(tr + row * 72 + part * 8);
    *(short8*)(AO + ((size_t)(b * SS + q0 + row)) * EE + h * 64 + part * 8) = ov;
  }
}

// ---------------------------------------------------------------------------
// Kernel 4: transpose Wo (fp32 [k][n]) -> WoT (bf16 [n][k]); runs after attn
// (aliases maskP region).
// ---------------------------------------------------------------------------
__global__ __launch_bounds__(256) void transpose_wo(
    const float* __restrict__ Wo, unsigned short* __restrict__ WoT)
{
  __shared__ unsigned short t[64 * 65];
  int tid = threadIdx.x;
  int k0 = (blockIdx.x >> 4) * 64;
  int n0 = (blockIdx.x & 15) * 64;
#pragma unroll
  for (int i = 0; i < 16; ++i) {
    int idx = tid + i * 256;
    int k = idx >> 6, n = idx & 63;
    t[n * 65 + k] = f2bf(Wo[(size_t)(k0 + k) * 1024 + n0 + n]);
  }
  __syncthreads();
#pragma unroll
  for (int i = 0; i < 16; ++i) {
    int idx = tid + i * 256;
    int n = idx >> 6, k = idx & 63;
    WoT[(size_t)(n0 + n) * 1024 + k0 + k] = t[n * 65 + k];
  }
}

// ---------------------------------------------------------------------------
// Kernel 5: out = AO(4096x1024 bf16) @ WoT^T + bo. 128m x 64n tile, BK=64,
// grid 512 (2 blocks/CU). Wave = 64m x 32n.
// ---------------------------------------------------------------------------
__global__ __launch_bounds__(256) void out_gemm(
    const unsigned short* __restrict__ AO, const unsigned short* __restrict__ WoT,
    const float* __restrict__ bo, float* __restrict__ out)
{
  __shared__ __align__(16) unsigned short at[128 * 72];
  __shared__ __align__(16) unsigned short bt[64 * 72];
  int tid = threadIdx.x, wv = tid >> 6, lane = tid & 63;
  int li = lane & 15, g = lane >> 4;
  int m0 = (blockIdx.x >> 4) * 128;
  int n0 = (blockIdx.x & 15) * 64;
  int wm = (wv & 1) * 64, wn = (wv >> 1) * 32;

  const unsigned short* Ag = AO + (size_t)m0 * 1024;
  const unsigned short* Bg = WoT + (size_t)n0 * 1024;
  int srow = tid >> 3, scol = (tid & 7) * 8;

  short8 apre[4], bpre[2];
  auto ldst = [&](int k0) {
#pragma unroll
    for (int i = 0; i < 4; ++i)
      apre[i] = *(const short8*)(Ag + (size_t)(srow + i * 32) * 1024 + k0 + scol);
#pragma unroll
    for (int i = 0; i < 2; ++i)
      bpre[i] = *(const short8*)(Bg + (size_t)(srow + i * 32) * 1024 + k0 + scol);
  };

  float4v acc[4][2];
#pragma unroll
  for (int mt = 0; mt < 4; ++mt)
#pragma unroll
    for (int nt = 0; nt < 2; ++nt) acc[mt][nt] = (float4v){0, 0, 0, 0};

  ldst(0);
  for (int k0 = 0; k0 < 1024; k0 += 64) {
    __syncthreads();
#pragma unroll
    for (int i = 0; i < 4; ++i)
      *(short8*)(at + (srow + i * 32) * 72 + scol) = apre[i];
#pragma unroll
    for (int i = 0; i < 2; ++i)
      *(short8*)(bt + (srow + i * 32) * 72 + scol) = bpre[i];
    int nk = (k0 + 64 < 1024) ? k0 + 64 : 0;
    ldst(nk);
    __syncthreads();
#pragma unroll
    for (int ks = 0; ks < 2; ++ks) {
      short8 afr[4], bfr[2];
#pragma unroll
      for (int mt = 0; mt < 4; ++mt)
        afr[mt] = *(const short8*)(at + (wm + mt * 16 + li) * 72 + ks * 32 + g * 8);
#pragma unroll
      for (int nt = 0; nt < 2; ++nt)
        bfr[nt] = *(const short8*)(bt + (wn + nt * 16 + li) * 72 + ks * 32 + g * 8);
#pragma unroll
      for (int mt = 0; mt < 4; ++mt)
#pragma unroll
        for (int nt = 0; nt < 2; ++nt)
          acc[mt][nt] = __builtin_amdgcn_mfma_f32_16x16x32_bf16(afr[mt], bfr[nt], acc[mt][nt], 0, 0, 0);
    }
  }
#pragma unroll
  for (int nt = 0; nt < 2; ++nt) {
    float bof = bo[n0 + wn + nt * 16 + li];
#pragma unroll
    for (int mt = 0; mt < 4; ++mt)
#pragma unroll
      for (int r = 0; r < 4; ++r)
        out[(size_t)(m0 + wm + mt * 16 + g * 4 + r) * 1024 + n0 + wn + nt * 16 + li] =
            acc[mt][nt][r] + bof;
  }
}

// ---------------------------------------------------------------------------
extern "C" void kernel_launch(void* const* d_in, const int* in_sizes, int n_in,
                              void* d_out, int out_size, void* d_ws, size_t ws_size,
                              hipStream_t stream) {
  const float* x    = (const float*)d_in[0];
  const float* mask = (const float*)d_in[1];
  const float* Wq   = (const float*)d_in[2];
  const float* bq   = (const float*)d_in[3];
  const float* Wk   = (const float*)d_in[4];
  const float* bk   = (const float*)d_in[5];
  const float* Wv   = (const float*)d_in[6];
  const float* bv   = (const float*)d_in[7];
  const float* Wo   = (const float*)d_in[8];
  const float* bo   = (const float*)d_in[9];
  float* out = (float*)d_out;

  unsigned short* ws = (unsigned short*)d_ws;
  unsigned short* Q     = ws;
  unsigned short* K     = ws + 4194304;
  unsigned short* Vp    = ws + 8388608;
  unsigned short* AO    = ws + 12582912;
  unsigned short* maskP = ws + 16777216;
  unsigned short* W3T = AO;      // dead until attn writes AO
  unsigned short* WoT = maskP;   // dead after attn reads maskP

  w3t_prep<<<3, 256, 0, stream>>>(Wq, Wk, Wv, W3T);
  qkv_kernel<<<512, 256, 0, stream>>>(x, W3T, bq, bk, bv, Q, K, Vp);
  mask_prep<<<2048, 256, 0, stream>>>(mask, maskP);
  attn_kernel<<<512, 256, 0, stream>>>(Q, K, Vp, maskP, AO);
  transpose_wo<<<256, 256, 0, stream>>>(Wo, WoT);
  out_gemm<<<512, 256, 0, stream>>>(AO, WoT, bo, out);
}